// Round 1
// baseline (779.775 us; speedup 1.0000x reference)
//
#include <hip/hip_runtime.h>

#define EPSF 1e-3f
constexpr int BHN = 64;    // B*H
constexpr int LN  = 4096;
constexpr int DN  = 64;
constexpr int MN  = 266;   // feature rows
constexpr int TS  = 68;    // LDS row stride (floats), float4-aligned pad
constexpr int TS4 = 17;    // LDS row stride (float4)

typedef float4 f4;

#define FMA16(ACC, P, VV)                                                        \
  ACC[0][0] += P.x*VV.x; ACC[0][1] += P.x*VV.y; ACC[0][2] += P.x*VV.z; ACC[0][3] += P.x*VV.w; \
  ACC[1][0] += P.y*VV.x; ACC[1][1] += P.y*VV.y; ACC[1][2] += P.y*VV.z; ACC[1][3] += P.y*VV.w; \
  ACC[2][0] += P.z*VV.x; ACC[2][1] += P.z*VV.y; ACC[2][2] += P.z*VV.z; ACC[2][3] += P.z*VV.w; \
  ACC[3][0] += P.w*VV.x; ACC[3][1] += P.w*VV.y; ACC[3][2] += P.w*VV.z; ACC[3][3] += P.w*VV.w;

// ---------------------------------------------------------------------------
// Kernel A: kv[bh][m][d] = sum_l kp[l][m]*v[l][d];  ksum[bh][m] = sum_l kp[l][m]
// grid (4 l-quarters, 5 m-chunks, 64 bh), 256 threads
// ---------------------------------------------------------------------------
__global__ __launch_bounds__(256) void perf_kv_kernel(
    const float* __restrict__ kg, const float* __restrict__ vg,
    const float* __restrict__ proj, float* __restrict__ kv_ws,
    float* __restrict__ ksum_ws)
{
  __shared__ __align__(16) float proj_lds[64*TS];  // [m][d]
  __shared__ __align__(16) float xv_lds[64*TS];    // K tile, then V tile [l][d]
  __shared__ __align__(16) float kp_lds[64*TS];    // [l][m]

  const int t   = threadIdx.x;
  const int lsp = blockIdx.x;   // 0..3
  const int mc  = blockIdx.y;   // 0..4
  const int bh  = blockIdx.z;   // 0..63
  const int m0  = mc * 64;

  // load proj chunk (coalesced; zero-pad m >= 266)
  for (int idx = t; idx < 64*64; idx += 256) {
    int m = idx >> 6, d = idx & 63;
    int gm = m0 + m;
    proj_lds[m*TS + d] = (gm < MN) ? proj[gm*DN + d] : 0.f;
  }

  const int lg = t & 15;   // phase1: l base = 4*lg
  const int mg = t >> 4;   // phase1: m base = 4*mg
  const int mq = t >> 4;   // phase2: m group (4*mq..+3)
  const int dq = t & 15;   // phase2: d group (4*dq..+3)

  float acc[4][4] = {{0.f,0.f,0.f,0.f},{0.f,0.f,0.f,0.f},{0.f,0.f,0.f,0.f},{0.f,0.f,0.f,0.f}};
  float ksum_reg = 0.f;

  const f4* projv = reinterpret_cast<const f4*>(proj_lds);
  const f4* xvv   = reinterpret_cast<const f4*>(xv_lds);
  const f4* kpv   = reinterpret_cast<const f4*>(kp_lds);

  for (int ls = 0; ls < 16; ++ls) {
    const int l0 = (lsp*16 + ls) * 64;
    __syncthreads();  // protect xv_lds (prev phase2) before K overwrite
    {
      const f4* kg4 = reinterpret_cast<const f4*>(kg) + ((size_t)bh*LN + l0) * (DN/4);
      for (int idx = t; idx < 64*16; idx += 256) {
        int l = idx >> 4, d4 = idx & 15;
        reinterpret_cast<f4*>(xv_lds)[l*TS4 + d4] = kg4[l*16 + d4];
      }
    }
    __syncthreads();
    // phase 1: kp = relu(K @ P^T) + eps
    float s[4][4] = {{0.f,0.f,0.f,0.f},{0.f,0.f,0.f,0.f},{0.f,0.f,0.f,0.f},{0.f,0.f,0.f,0.f}};
#pragma unroll
    for (int d4 = 0; d4 < 16; ++d4) {
      f4 a[4], b[4];
#pragma unroll
      for (int i = 0; i < 4; ++i) a[i] = xvv[(4*lg+i)*TS4 + d4];
#pragma unroll
      for (int j = 0; j < 4; ++j) b[j] = projv[(4*mg+j)*TS4 + d4];
#pragma unroll
      for (int i = 0; i < 4; ++i)
#pragma unroll
        for (int j = 0; j < 4; ++j)
          s[i][j] += a[i].x*b[j].x + a[i].y*b[j].y + a[i].z*b[j].z + a[i].w*b[j].w;
    }
#pragma unroll
    for (int i = 0; i < 4; ++i) {
      f4 w;
      w.x = fmaxf(s[i][0], 0.f) + EPSF;
      w.y = fmaxf(s[i][1], 0.f) + EPSF;
      w.z = fmaxf(s[i][2], 0.f) + EPSF;
      w.w = fmaxf(s[i][3], 0.f) + EPSF;
      reinterpret_cast<f4*>(kp_lds)[(4*lg+i)*TS4 + mg] = w;
    }
    __syncthreads();  // kp ready; K reads done -> xv_lds reusable
    {
      const f4* vg4 = reinterpret_cast<const f4*>(vg) + ((size_t)bh*LN + l0) * (DN/4);
      for (int idx = t; idx < 64*16; idx += 256) {
        int l = idx >> 4, d4 = idx & 15;
        reinterpret_cast<f4*>(xv_lds)[l*TS4 + d4] = vg4[l*16 + d4];
      }
    }
    if (t < 64) {  // ksum partial for m_local = t
#pragma unroll 8
      for (int l = 0; l < 64; ++l) ksum_reg += kp_lds[l*TS + t];
    }
    __syncthreads();  // V ready
    // phase 2: kv += kp^T @ V
#pragma unroll 8
    for (int l = 0; l < 64; ++l) {
      f4 p  = kpv[l*TS4 + mq];
      f4 vv = xvv[l*TS4 + dq];
      FMA16(acc, p, vv)
    }
  }

#pragma unroll
  for (int i = 0; i < 4; ++i) {
    int m = m0 + 4*mq + i;
    if (m < MN) {
#pragma unroll
      for (int j = 0; j < 4; ++j)
        atomicAdd(&kv_ws[((size_t)bh*MN + m)*DN + 4*dq + j], acc[i][j]);
    }
  }
  if (t < 64 && (m0 + t) < MN) atomicAdd(&ksum_ws[bh*MN + m0 + t], ksum_reg);
}

// ---------------------------------------------------------------------------
// Kernel B: qp = relu(Q @ P^T)+eps; d = qp.ksum; out = (qp @ kv) / d
// grid (64 l-tiles, 64 bh), 256 threads
// ---------------------------------------------------------------------------
__global__ __launch_bounds__(256) void perf_out_kernel(
    const float* __restrict__ qg, const float* __restrict__ proj,
    const float* __restrict__ kv_ws, const float* __restrict__ ksum_ws,
    float* __restrict__ outg)
{
  __shared__ __align__(16) float q_lds[64*TS];    // [l][d]
  __shared__ __align__(16) float pk_lds[64*TS];   // proj chunk, then kv chunk
  __shared__ __align__(16) float qpT_lds[64*TS];  // [m][l] (transposed)
  __shared__ float ksum_lds[64];
  __shared__ float d_lds[64];

  const int t  = threadIdx.x;
  const int lb = blockIdx.x;  // 0..63
  const int bh = blockIdx.y;  // 0..63
  const int l0 = lb * 64;

  {
    const f4* qg4 = reinterpret_cast<const f4*>(qg) + ((size_t)bh*LN + l0) * (DN/4);
    for (int idx = t; idx < 64*16; idx += 256) {
      int l = idx >> 4, d4 = idx & 15;
      reinterpret_cast<f4*>(q_lds)[l*TS4 + d4] = qg4[l*16 + d4];
    }
  }

  const int lg = t & 15, mg = t >> 4;  // phase1
  const int lq = t >> 4, dq = t & 15;  // phase2 + store (dq fast -> coalesced)

  float acc[4][4] = {{0.f,0.f,0.f,0.f},{0.f,0.f,0.f,0.f},{0.f,0.f,0.f,0.f},{0.f,0.f,0.f,0.f}};
  float d_acc = 0.f;

  const f4* qv  = reinterpret_cast<const f4*>(q_lds);
  const f4* pkv = reinterpret_cast<const f4*>(pk_lds);
  const f4* qpv = reinterpret_cast<const f4*>(qpT_lds);

  for (int mcI = 0; mcI < 5; ++mcI) {
    const int m0 = mcI * 64;
    __syncthreads();  // prev chunk readers done
    for (int idx = t; idx < 64*64; idx += 256) {
      int m = idx >> 6, d = idx & 63;
      int gm = m0 + m;
      pk_lds[m*TS + d] = (gm < MN) ? proj[gm*DN + d] : 0.f;
    }
    if (t < 64) {
      int gm = m0 + t;
      ksum_lds[t] = (gm < MN) ? ksum_ws[bh*MN + gm] : 0.f;
    }
    __syncthreads();
    // phase 1: qp chunk, stored transposed [m][l]
    float s[4][4] = {{0.f,0.f,0.f,0.f},{0.f,0.f,0.f,0.f},{0.f,0.f,0.f,0.f},{0.f,0.f,0.f,0.f}};
#pragma unroll
    for (int d4 = 0; d4 < 16; ++d4) {
      f4 a[4], b[4];
#pragma unroll
      for (int i = 0; i < 4; ++i) a[i] = qv[(4*lg+i)*TS4 + d4];
#pragma unroll
      for (int j = 0; j < 4; ++j) b[j] = pkv[(4*mg+j)*TS4 + d4];
#pragma unroll
      for (int i = 0; i < 4; ++i)
#pragma unroll
        for (int j = 0; j < 4; ++j)
          s[i][j] += a[i].x*b[j].x + a[i].y*b[j].y + a[i].z*b[j].z + a[i].w*b[j].w;
    }
#pragma unroll
    for (int j = 0; j < 4; ++j) {
      f4 w;
      w.x = fmaxf(s[0][j], 0.f) + EPSF;
      w.y = fmaxf(s[1][j], 0.f) + EPSF;
      w.z = fmaxf(s[2][j], 0.f) + EPSF;
      w.w = fmaxf(s[3][j], 0.f) + EPSF;
      reinterpret_cast<f4*>(qpT_lds)[(4*mg+j)*TS4 + lg] = w;
    }
    __syncthreads();  // qp ready; proj reads done -> pk_lds reusable
    // load kv chunk (zeros for padded m; never read OOB workspace)
    for (int idx = t; idx < 64*16; idx += 256) {
      int m = idx >> 4, d4 = idx & 15;
      f4 z = {0.f, 0.f, 0.f, 0.f};
      int gm = m0 + m;
      if (gm < MN) z = reinterpret_cast<const f4*>(kv_ws)[((size_t)bh*MN + gm)*16 + d4];
      reinterpret_cast<f4*>(pk_lds)[m*TS4 + d4] = z;
    }
    if (t < 64) {  // d partial for l = t
#pragma unroll 8
      for (int m = 0; m < 64; ++m) d_acc += qpT_lds[m*TS + t] * ksum_lds[m];
    }
    __syncthreads();  // kv ready
    // phase 2: out += qp @ kv
#pragma unroll 8
    for (int m = 0; m < 64; ++m) {
      f4 p   = qpv[m*TS4 + lq];
      f4 kvv = pkv[m*TS4 + dq];
      FMA16(acc, p, kvv)
    }
  }

  if (t < 64) d_lds[t] = d_acc;
  __syncthreads();

  f4* out4 = reinterpret_cast<f4*>(outg) + ((size_t)bh*LN + l0) * (DN/4);
#pragma unroll
  for (int i = 0; i < 4; ++i) {
    float dinv = 1.0f / d_lds[4*lq + i];
    f4 w;
    w.x = acc[i][0]*dinv; w.y = acc[i][1]*dinv; w.z = acc[i][2]*dinv; w.w = acc[i][3]*dinv;
    out4[(4*lq + i)*16 + dq] = w;
  }
}

// ---------------------------------------------------------------------------
extern "C" void kernel_launch(void* const* d_in, const int* in_sizes, int n_in,
                              void* d_out, int out_size, void* d_ws, size_t ws_size,
                              hipStream_t stream)
{
  const float* q    = (const float*)d_in[0];
  const float* k    = (const float*)d_in[1];
  const float* v    = (const float*)d_in[2];
  const float* proj = (const float*)d_in[3];
  float* out     = (float*)d_out;
  float* kv_ws   = (float*)d_ws;
  float* ksum_ws = kv_ws + (size_t)BHN*MN*DN;

  size_t zero_bytes = ((size_t)BHN*MN*DN + (size_t)BHN*MN) * sizeof(float);
  hipMemsetAsync(d_ws, 0, zero_bytes, stream);

  perf_kv_kernel<<<dim3(4, 5, BHN), 256, 0, stream>>>(k, v, proj, kv_ws, ksum_ws);
  perf_out_kernel<<<dim3(LN/64, BHN), 256, 0, stream>>>(q, proj, kv_ws, ksum_ws, out);
}

// Round 2
// 179.193 us; speedup vs baseline: 4.3516x; 4.3516x over previous
//
#include <hip/hip_runtime.h>

typedef __bf16 bf16;
typedef bf16 bf16x2 __attribute__((ext_vector_type(2)));
typedef bf16 bf16x4 __attribute__((ext_vector_type(4)));
typedef bf16 bf16x8 __attribute__((ext_vector_type(8)));
typedef float f32x4 __attribute__((ext_vector_type(4)));
typedef float4 f4;

constexpr int BHN = 64;   // B*H
constexpr int LN  = 4096;
constexpr int DN  = 64;
constexpr int MN  = 266;  // real feature rows
constexpr int MP  = 320;  // padded to 5*64 (zero proj rows; numerically negligible)
constexpr int STR = 72;   // LDS row stride in bf16 (144B: multiple of 16B, conflict-free frag reads)
#define EPSF 1e-3f

// ---------------------------------------------------------------------------
// Kernel A: kvT[bh][d][m] = sum_l V[l][d]*kp[l][m],  ksum[bh][m] = sum_l kp[l][m]
//   kp[l][m] = relu(K[l][:]·proj[m][:]) + eps
// grid (8 l-chunks, 64 bh) x 256 threads (4 waves; wave w owns m in [80w,80w+80))
// ---------------------------------------------------------------------------
__global__ __launch_bounds__(256, 2) void perf_kv_mfma(
    const float* __restrict__ kg, const float* __restrict__ vg,
    const float* __restrict__ proj, float* __restrict__ kv_ws,
    float* __restrict__ ksum_ws)
{
  __shared__ __align__(16) bf16 proj_lds[MP * STR];   // [m][d]
  __shared__ __align__(16) bf16 k_lds[64 * STR];      // [l][d]
  __shared__ __align__(16) bf16 vt_lds[64 * STR];     // [d][l]  (transposed V)
  __shared__ __align__(16) bf16 kp_lds[4 * 16 * STR]; // per-wave [16 m][64 l]

  const int t    = threadIdx.x;
  const int wid  = t >> 6;
  const int lane = t & 63;
  const int c    = lane & 15;   // fragment row/col index
  const int g    = lane >> 4;   // k-group / reg-group
  const int lsp  = blockIdx.x;  // 0..7
  const int bh   = blockIdx.y;  // 0..63

  // stage full proj -> bf16 LDS [m][d] (zero-padded m >= 266)
  const f4* projv = reinterpret_cast<const f4*>(proj);
  for (int idx = t; idx < MP * 16; idx += 256) {
    int m = idx >> 4, d4 = idx & 15;
    f4 val = {0.f, 0.f, 0.f, 0.f};
    if (m < MN) val = projv[m * 16 + d4];
    bf16x4 w = {(bf16)val.x, (bf16)val.y, (bf16)val.z, (bf16)val.w};
    *(bf16x4*)&proj_lds[m * STR + d4 * 4] = w;
  }

  f32x4 acc[4][5];  // [dt][mt] : kvT rows d = dt*16+g*4+reg, col m = wid*80+mt*16+c
#pragma unroll
  for (int dt = 0; dt < 4; ++dt)
#pragma unroll
    for (int mt = 0; mt < 5; ++mt) acc[dt][mt] = (f32x4){0.f, 0.f, 0.f, 0.f};
  float ksum_acc[5] = {0.f, 0.f, 0.f, 0.f, 0.f};

  bf16* kpw = kp_lds + wid * 16 * STR;

  for (int ls = 0; ls < 8; ++ls) {
    const int l0 = (lsp * 8 + ls) * 64;
    __syncthreads();  // previous tile fully consumed
    // stage K tile [64 l][64 d] f32->bf16
    {
      const f4* kg4 = reinterpret_cast<const f4*>(kg) + ((size_t)bh * LN + l0) * 16;
      for (int idx = t; idx < 64 * 16; idx += 256) {
        int l = idx >> 4, d4 = idx & 15;
        f4 val = kg4[l * 16 + d4];
        bf16x4 w = {(bf16)val.x, (bf16)val.y, (bf16)val.z, (bf16)val.w};
        *(bf16x4*)&k_lds[l * STR + d4 * 4] = w;
      }
    }
    // stage V transposed: vt[d][l] (register-packed 4-row transpose)
    {
      const float* vbase = vg + ((size_t)bh * LN + l0) * DN;
      const int d = t & 63, grp = t >> 6;
#pragma unroll
      for (int i = 0; i < 4; ++i) {
        int lb = grp * 16 + i * 4;
        float x0 = vbase[(lb + 0) * 64 + d];
        float x1 = vbase[(lb + 1) * 64 + d];
        float x2 = vbase[(lb + 2) * 64 + d];
        float x3 = vbase[(lb + 3) * 64 + d];
        bf16x4 w = {(bf16)x0, (bf16)x1, (bf16)x2, (bf16)x3};
        *(bf16x4*)&vt_lds[d * STR + lb] = w;
      }
    }
    __syncthreads();  // K, vT ready

    // preload fragments constant over the mtile loop
    bf16x8 va[4][2], ka[4][2];
#pragma unroll
    for (int dt = 0; dt < 4; ++dt)
#pragma unroll
      for (int s = 0; s < 2; ++s)
        va[dt][s] = *(const bf16x8*)&vt_lds[(dt * 16 + c) * STR + s * 32 + g * 8];
#pragma unroll
    for (int lt = 0; lt < 4; ++lt)
#pragma unroll
      for (int s = 0; s < 2; ++s)
        ka[lt][s] = *(const bf16x8*)&k_lds[(lt * 16 + c) * STR + s * 32 + g * 8];

#pragma unroll
    for (int mt = 0; mt < 5; ++mt) {
      const int m0 = wid * 80 + mt * 16;
      // feature: C1[l][m0+c] = K·projT  (rows l, cols m)
      bf16x8 pb0 = *(const bf16x8*)&proj_lds[(m0 + c) * STR + g * 8];
      bf16x8 pb1 = *(const bf16x8*)&proj_lds[(m0 + c) * STR + 32 + g * 8];
      f32x4 fa[4];
#pragma unroll
      for (int lt = 0; lt < 4; ++lt) {
        fa[lt] = (f32x4){0.f, 0.f, 0.f, 0.f};
        fa[lt] = __builtin_amdgcn_mfma_f32_16x16x32_bf16(ka[lt][0], pb0, fa[lt], 0, 0, 0);
        fa[lt] = __builtin_amdgcn_mfma_f32_16x16x32_bf16(ka[lt][1], pb1, fa[lt], 0, 0, 0);
      }
      float kpart = 0.f;
#pragma unroll
      for (int lt = 0; lt < 4; ++lt) {
        f32x4 f = fa[lt];
        f.x = fmaxf(f.x, 0.f) + EPSF;
        f.y = fmaxf(f.y, 0.f) + EPSF;
        f.z = fmaxf(f.z, 0.f) + EPSF;
        f.w = fmaxf(f.w, 0.f) + EPSF;
        kpart += f.x + f.y + f.z + f.w;  // sum over this lane's 4 l rows
        bf16x4 w = {(bf16)f.x, (bf16)f.y, (bf16)f.z, (bf16)f.w};
        *(bf16x4*)&kpw[c * STR + lt * 16 + g * 4] = w;  // kp[m=c][l rows] wave-private
      }
      ksum_acc[mt] += kpart;
      // kv: kvT[d][m0+c] += vT·kp   (A = vT[d][l], B = kp[m][l])
#pragma unroll
      for (int s = 0; s < 2; ++s) {
        bf16x8 kb = *(const bf16x8*)&kpw[c * STR + s * 32 + g * 8];
#pragma unroll
        for (int dt = 0; dt < 4; ++dt)
          acc[dt][mt] = __builtin_amdgcn_mfma_f32_16x16x32_bf16(va[dt][s], kb, acc[dt][mt], 0, 0, 0);
      }
    }
  }

  // epilogue: accumulate into workspace
#pragma unroll
  for (int mt = 0; mt < 5; ++mt) {
    const int m = wid * 80 + mt * 16 + c;
#pragma unroll
    for (int dt = 0; dt < 4; ++dt) {
      f32x4 a = acc[dt][mt];
      const int db = dt * 16 + g * 4;
      atomicAdd(&kv_ws[((size_t)bh * 64 + db + 0) * MP + m], a.x);
      atomicAdd(&kv_ws[((size_t)bh * 64 + db + 1) * MP + m], a.y);
      atomicAdd(&kv_ws[((size_t)bh * 64 + db + 2) * MP + m], a.z);
      atomicAdd(&kv_ws[((size_t)bh * 64 + db + 3) * MP + m], a.w);
    }
    float r = ksum_acc[mt];
    r += __shfl_xor(r, 16);
    r += __shfl_xor(r, 32);
    if (g == 0) atomicAdd(&ksum_ws[bh * MP + m], r);
  }
}

// ---------------------------------------------------------------------------
// Kernel B: qp = relu(Q·projT)+eps; d = qp·ksum; out[l][d] = (qp·kv)[l][d]/d[l]
// grid (64 l-tiles, 64 bh) x 256 threads (wave w owns l rows [16w,16w+16))
// ---------------------------------------------------------------------------
__global__ __launch_bounds__(256, 4) void perf_out_mfma(
    const float* __restrict__ qg, const float* __restrict__ proj,
    const float* __restrict__ kv_ws, const float* __restrict__ ksum_ws,
    float* __restrict__ outg)
{
  __shared__ __align__(16) bf16 q_lds[64 * STR];   // [l][d]
  __shared__ __align__(16) bf16 pj_lds[64 * STR];  // proj chunk [m][d]
  __shared__ __align__(16) bf16 kv_lds[64 * STR];  // kvT chunk [d][m]
  __shared__ __align__(16) bf16 qp_lds[64 * STR];  // [l][m] (wave-private rows)
  __shared__ float ksum_lds[64];
  __shared__ float d_lds[64];

  const int t    = threadIdx.x;
  const int wid  = t >> 6;
  const int lane = t & 63;
  const int c    = lane & 15;
  const int g    = lane >> 4;
  const int lb   = blockIdx.x;
  const int bh   = blockIdx.y;
  const int l0   = lb * 64;

  // stage Q tile
  {
    const f4* qg4 = reinterpret_cast<const f4*>(qg) + ((size_t)bh * LN + l0) * 16;
    for (int idx = t; idx < 64 * 16; idx += 256) {
      int l = idx >> 4, d4 = idx & 15;
      f4 val = qg4[l * 16 + d4];
      bf16x4 w = {(bf16)val.x, (bf16)val.y, (bf16)val.z, (bf16)val.w};
      *(bf16x4*)&q_lds[l * STR + d4 * 4] = w;
    }
  }
  __syncthreads();

  // B-operand of feature (Q rows = this wave's l range) is loop-invariant
  bf16x8 qb0 = *(const bf16x8*)&q_lds[(wid * 16 + c) * STR + g * 8];
  bf16x8 qb1 = *(const bf16x8*)&q_lds[(wid * 16 + c) * STR + 32 + g * 8];

  f32x4 oacc[4];  // [dt]: rows l = wid*16+g*4+reg, col d = dt*16+c
#pragma unroll
  for (int dt = 0; dt < 4; ++dt) oacc[dt] = (f32x4){0.f, 0.f, 0.f, 0.f};
  float dp = 0.f;

  const f4* projv = reinterpret_cast<const f4*>(proj);

  for (int mc = 0; mc < 5; ++mc) {
    const int m0 = mc * 64;
    __syncthreads();  // previous chunk fully consumed
    // stage proj chunk [m][d]
    for (int idx = t; idx < 64 * 16; idx += 256) {
      int m = idx >> 4, d4 = idx & 15;
      int gm = m0 + m;
      f4 val = {0.f, 0.f, 0.f, 0.f};
      if (gm < MN) val = projv[gm * 16 + d4];
      bf16x4 w = {(bf16)val.x, (bf16)val.y, (bf16)val.z, (bf16)val.w};
      *(bf16x4*)&pj_lds[m * STR + d4 * 4] = w;
    }
    // stage kvT chunk [d][m] from f32 workspace
    {
      const float2* kv2 = reinterpret_cast<const float2*>(kv_ws);
      for (int idx = t; idx < 64 * 32; idx += 256) {
        int d = idx >> 5, mp = idx & 31;
        float2 v = kv2[(((size_t)bh * 64 + d) * MP + m0) / 2 + mp];
        bf16x2 w = {(bf16)v.x, (bf16)v.y};
        *(bf16x2*)&kv_lds[d * STR + mp * 2] = w;
      }
    }
    if (t < 64) ksum_lds[t] = ksum_ws[bh * MP + m0 + t];
    __syncthreads();

    // feature: C2[m][l] = proj·QT ; rows m, cols l (this wave's 16 l)
#pragma unroll
    for (int mt = 0; mt < 4; ++mt) {
      bf16x8 pa0 = *(const bf16x8*)&pj_lds[(mt * 16 + c) * STR + g * 8];
      bf16x8 pa1 = *(const bf16x8*)&pj_lds[(mt * 16 + c) * STR + 32 + g * 8];
      f32x4 fa = (f32x4){0.f, 0.f, 0.f, 0.f};
      fa = __builtin_amdgcn_mfma_f32_16x16x32_bf16(pa0, qb0, fa, 0, 0, 0);
      fa = __builtin_amdgcn_mfma_f32_16x16x32_bf16(pa1, qb1, fa, 0, 0, 0);
      fa.x = fmaxf(fa.x, 0.f) + EPSF;
      fa.y = fmaxf(fa.y, 0.f) + EPSF;
      fa.z = fmaxf(fa.z, 0.f) + EPSF;
      fa.w = fmaxf(fa.w, 0.f) + EPSF;
      const int mb = mt * 16 + g * 4;  // local m of this lane's 4 rows
      dp += fa.x * ksum_lds[mb + 0] + fa.y * ksum_lds[mb + 1] +
            fa.z * ksum_lds[mb + 2] + fa.w * ksum_lds[mb + 3];
      bf16x4 w = {(bf16)fa.x, (bf16)fa.y, (bf16)fa.z, (bf16)fa.w};
      *(bf16x4*)&qp_lds[(wid * 16 + c) * STR + mb] = w;  // qp[l][m] wave-private row
    }
    // out: A = qp[l][m], B = kvT[d][m]
#pragma unroll
    for (int s = 0; s < 2; ++s) {
      bf16x8 qa = *(const bf16x8*)&qp_lds[(wid * 16 + c) * STR + s * 32 + g * 8];
#pragma unroll
      for (int dt = 0; dt < 4; ++dt) {
        bf16x8 kb = *(const bf16x8*)&kv_lds[(dt * 16 + c) * STR + s * 32 + g * 8];
        oacc[dt] = __builtin_amdgcn_mfma_f32_16x16x32_bf16(qa, kb, oacc[dt], 0, 0, 0);
      }
    }
  }

  // denominator: dp covers this lane's m rows for column l = wid*16+c
  dp += __shfl_xor(dp, 16);
  dp += __shfl_xor(dp, 32);
  if (g == 0) d_lds[wid * 16 + c] = dp;
  __syncthreads();

  const int lrow = wid * 16 + g * 4;
  float dinv0 = 1.f / d_lds[lrow + 0];
  float dinv1 = 1.f / d_lds[lrow + 1];
  float dinv2 = 1.f / d_lds[lrow + 2];
  float dinv3 = 1.f / d_lds[lrow + 3];

  float* ob = outg + ((size_t)bh * LN + l0) * DN;
#pragma unroll
  for (int dt = 0; dt < 4; ++dt) {
    f32x4 a = oacc[dt];
    const int dcol = dt * 16 + c;
    ob[(lrow + 0) * 64 + dcol] = a.x * dinv0;
    ob[(lrow + 1) * 64 + dcol] = a.y * dinv1;
    ob[(lrow + 2) * 64 + dcol] = a.z * dinv2;
    ob[(lrow + 3) * 64 + dcol] = a.w * dinv3;
  }
}

// ---------------------------------------------------------------------------
extern "C" void kernel_launch(void* const* d_in, const int* in_sizes, int n_in,
                              void* d_out, int out_size, void* d_ws, size_t ws_size,
                              hipStream_t stream)
{
  const float* q    = (const float*)d_in[0];
  const float* k    = (const float*)d_in[1];
  const float* v    = (const float*)d_in[2];
  const float* proj = (const float*)d_in[3];
  float* out     = (float*)d_out;
  float* kv_ws   = (float*)d_ws;                       // [64][64][320] f32
  float* ksum_ws = kv_ws + (size_t)BHN * DN * MP;      // [64][320] f32

  size_t zero_bytes = ((size_t)BHN * DN * MP + (size_t)BHN * MP) * sizeof(float);
  hipMemsetAsync(d_ws, 0, zero_bytes, stream);

  perf_kv_mfma<<<dim3(8, BHN), 256, 0, stream>>>(k, v, proj, kv_ws, ksum_ws);
  perf_out_mfma<<<dim3(LN / 64, BHN), 256, 0, stream>>>(q, proj, kv_ws, ksum_ws, out);
}